// Round 3
// baseline (502.927 us; speedup 1.0000x reference)
//
#include <hip/hip_runtime.h>
#include <hip/hip_bf16.h>
#include <math.h>

typedef unsigned short ushort_t;
typedef __attribute__((ext_vector_type(8))) __bf16 bf16x8;
typedef __attribute__((ext_vector_type(4))) float f32x4;
typedef __attribute__((ext_vector_type(4))) unsigned int u32x4;

#define E_DIM 512
#define HEADS 8
#define HD 64
#define SEQ 2048
#define NROWS 8192        // B * SEQ
#define SCALE_F 0.125f
#define NEGF (-1e30f)

static __device__ __forceinline__ unsigned short f2b(float f) {
  unsigned int x;
  __builtin_memcpy(&x, &f, 4);
  x += 0x7fffu + ((x >> 16) & 1u);   // round-to-nearest-even
  return (unsigned short)(x >> 16);
}

// ---------------- weight transpose + cast: WT[n][k] = bf16(W[k][n]), 512x512 ----------------
__launch_bounds__(256)
__global__ void transpose512(const float* __restrict__ in, ushort_t* __restrict__ out) {
  __shared__ float tile[32 * 33];
  int t = threadIdx.x;
  int tx = t & 31, ty = t >> 5;            // 32 x 8
  int n0 = blockIdx.x * 32, k0 = blockIdx.y * 32;
#pragma unroll
  for (int i = 0; i < 4; ++i) {
    int k = ty + i * 8;
    tile[k * 33 + tx] = in[(k0 + k) * E_DIM + n0 + tx];
  }
  __syncthreads();
#pragma unroll
  for (int i = 0; i < 4; ++i) {
    int n = ty + i * 8;
    out[(n0 + n) * E_DIM + k0 + tx] = f2b(tile[tx * 33 + n]);
  }
}

// ---------------- LayerNorm: wave per row (512 fp32 elems, 8/lane), bf16 out ----------------
__launch_bounds__(256)
__global__ void ln_kernel(const float* __restrict__ x, const float* __restrict__ g,
                          const float* __restrict__ bb, ushort_t* __restrict__ y) {
  int t = threadIdx.x, w = t >> 6, l = t & 63;
  int row = blockIdx.x * 4 + w;
  f32x4 x0 = *(const f32x4*)&x[row * E_DIM + l * 8];
  f32x4 x1 = *(const f32x4*)&x[row * E_DIM + l * 8 + 4];
  float xf[8];
  float s = 0.f, ss = 0.f;
#pragma unroll
  for (int j = 0; j < 8; ++j) {
    xf[j] = (j < 4) ? x0[j] : x1[j - 4];
    s += xf[j];
    ss += xf[j] * xf[j];
  }
#pragma unroll
  for (int off = 32; off > 0; off >>= 1) {
    s += __shfl_xor(s, off);
    ss += __shfl_xor(ss, off);
  }
  float mu = s * (1.f / 512.f);
  float var = fmaxf(ss * (1.f / 512.f) - mu * mu, 0.f);
  float rs = rsqrtf(var + 1e-5f);
  f32x4 g0 = *(const f32x4*)&g[l * 8];
  f32x4 g1 = *(const f32x4*)&g[l * 8 + 4];
  f32x4 b0 = *(const f32x4*)&bb[l * 8];
  f32x4 b1 = *(const f32x4*)&bb[l * 8 + 4];
#pragma unroll
  for (int j = 0; j < 8; ++j) {
    float gv = (j < 4) ? g0[j] : g1[j - 4];
    float bv = (j < 4) ? b0[j] : b1[j - 4];
    y[row * E_DIM + l * 8 + j] = f2b((xf[j] - mu) * rs * gv + bv);
  }
}

// ---------------- GEMM: C[M,512] = A[M,512] @ WT^T + bias (bf16 in, OUT_T out) ----------------
// WT is (N,K) row-major bf16 (pre-transposed). 64x64 tile, BK=32, 256 thr / 4 waves.
template <typename OUT_T>
__launch_bounds__(256)
__global__ void gemm_bias(const ushort_t* __restrict__ A, const ushort_t* __restrict__ WT,
                          const float* __restrict__ bias, OUT_T* __restrict__ C) {
  __shared__ ushort_t lA[64 * 32];
  __shared__ ushort_t lB[64 * 32];
  int t = threadIdx.x, w = t >> 6, l = t & 63;
  int quad = l >> 4, l15 = l & 15;
  int m0 = blockIdx.x * 64, n0 = blockIdx.y * 64;

  f32x4 acc[4] = {};
  const ushort_t* ga = A + (m0 + (t >> 2)) * E_DIM + (t & 3) * 8;
  const ushort_t* gb = WT + (n0 + (t >> 2)) * E_DIM + (t & 3) * 8;
  int sidx = (t >> 2) * 32 + (t & 3) * 8;

  for (int kk = 0; kk < E_DIM; kk += 32) {
    *(u32x4*)&lA[sidx] = *(const u32x4*)(ga + kk);
    *(u32x4*)&lB[sidx] = *(const u32x4*)(gb + kk);
    __syncthreads();
    bf16x8 a = *(const bf16x8*)&lA[(w * 16 + l15) * 32 + quad * 8];
#pragma unroll
    for (int nt = 0; nt < 4; ++nt) {
      bf16x8 b = *(const bf16x8*)&lB[(nt * 16 + l15) * 32 + quad * 8];
      acc[nt] = __builtin_amdgcn_mfma_f32_16x16x32_bf16(a, b, acc[nt], 0, 0, 0);
    }
    __syncthreads();
  }
#pragma unroll
  for (int nt = 0; nt < 4; ++nt) {
    int col = n0 + nt * 16 + l15;
    float bv = bias[col];
#pragma unroll
    for (int r = 0; r < 4; ++r) {
      int rowm = m0 + w * 16 + quad * 4 + r;   // C/D: col=lane&15, row=quad*4+r (m89)
      float val = acc[nt][r] + bv;
      if constexpr (sizeof(OUT_T) == 2)
        C[rowm * E_DIM + col] = f2b(val);
      else
        C[rowm * E_DIM + col] = val;
    }
  }
}

// ---------------- flash attention: block per (b, h, 64-row q-tile) ----------------
__launch_bounds__(256)
__global__ void attn_kernel(const ushort_t* __restrict__ Qp, const ushort_t* __restrict__ Kp,
                            const ushort_t* __restrict__ Vp, const int* __restrict__ kvm_g,
                            const int* __restrict__ sp_g, ushort_t* __restrict__ ctx) {
  __shared__ ushort_t sQ[64 * 64];
  __shared__ ushort_t sK[64 * 64];
  __shared__ ushort_t sV[64 * 64];
  __shared__ ushort_t sP[64 * 64];
  int t = threadIdx.x, w = t >> 6, l = t & 63;
  int quad = l >> 4, l15 = l & 15;
  int q0 = blockIdx.x * 64;
  int h = blockIdx.y;
  int b = blockIdx.z;

  // stage Q tile (64 rows x 64 d)
#pragma unroll
  for (int it = 0; it < 2; ++it) {
    int row = it * 32 + (t >> 3), d = (t & 7) * 8;
    *(u32x4*)&sQ[row * 64 + d] =
        *(const u32x4*)&Qp[(size_t)(b * SEQ + q0 + row) * E_DIM + h * HD + d];
  }

  float m[4], lsum[4];
  f32x4 o[4] = {};
#pragma unroll
  for (int r = 0; r < 4; ++r) { m[r] = NEGF; lsum[r] = 0.f; }

  for (int kt = 0; kt < 32; ++kt) {
    int k0 = kt * 64;
    __syncthreads();   // previous PV reads of sK/sV done
#pragma unroll
    for (int it = 0; it < 2; ++it) {
      int row = it * 32 + (t >> 3), d = (t & 7) * 8;
      size_t gidx = (size_t)(b * SEQ + k0 + row) * E_DIM + h * HD + d;
      *(u32x4*)&sK[row * 64 + d] = *(const u32x4*)&Kp[gidx];
      *(u32x4*)&sV[row * 64 + d] = *(const u32x4*)&Vp[gidx];
    }
    __syncthreads();

    // S = Q K^T  (64x64, wave w owns rows w*16..+16)
    f32x4 s[4] = {};
#pragma unroll
    for (int ks = 0; ks < 2; ++ks) {
      bf16x8 a = *(const bf16x8*)&sQ[(w * 16 + l15) * 64 + ks * 32 + quad * 8];
#pragma unroll
      for (int nt = 0; nt < 4; ++nt) {
        bf16x8 bfr = *(const bf16x8*)&sK[(nt * 16 + l15) * 64 + ks * 32 + quad * 8];
        s[nt] = __builtin_amdgcn_mfma_f32_16x16x32_bf16(a, bfr, s[nt], 0, 0, 0);
      }
    }

    // masks + online softmax (row-state replicated across the quad's 16 lanes)
    int kvmv[4];
#pragma unroll
    for (int nt = 0; nt < 4; ++nt) kvmv[nt] = kvm_g[b * SEQ + k0 + nt * 16 + l15];

#pragma unroll
    for (int r = 0; r < 4; ++r) {
      int qrow = q0 + w * 16 + quad * 4 + r;
      const int* sp = sp_g + (size_t)(b * SEQ + qrow) * SEQ + k0;
      float sv[4];
      bool ok[4];
      float vm = NEGF;
#pragma unroll
      for (int nt = 0; nt < 4; ++nt) {
        ok[nt] = (kvmv[nt] != 0) && (sp[nt * 16 + l15] != 0);
        sv[nt] = s[nt][r] * SCALE_F;
        if (ok[nt]) vm = fmaxf(vm, sv[nt]);
      }
#pragma unroll
      for (int off = 1; off < 16; off <<= 1) vm = fmaxf(vm, __shfl_xor(vm, off));
      float mnew = fmaxf(m[r], vm);
      float alpha = __expf(m[r] - mnew);   // both NEGF -> exp(0)=1; finite gap -> correct
      float ps = 0.f;
#pragma unroll
      for (int nt = 0; nt < 4; ++nt) {
        float pv = ok[nt] ? __expf(sv[nt] - mnew) : 0.f;
        ps += pv;
        sP[(w * 16 + quad * 4 + r) * 64 + nt * 16 + l15] = f2b(pv);
      }
#pragma unroll
      for (int off = 1; off < 16; off <<= 1) ps += __shfl_xor(ps, off);
      lsum[r] = lsum[r] * alpha + ps;
      m[r] = mnew;
#pragma unroll
      for (int nt = 0; nt < 4; ++nt) o[nt][r] *= alpha;
    }
    __syncthreads();   // sP visible / ordered before PV

    // O += P @ V   (A-frag from sP contiguous; B-frag from sV strided scalar reads)
#pragma unroll
    for (int ks = 0; ks < 2; ++ks) {
      bf16x8 a = *(const bf16x8*)&sP[(w * 16 + l15) * 64 + ks * 32 + quad * 8];
#pragma unroll
      for (int nt = 0; nt < 4; ++nt) {
        union { ushort_t u[8]; bf16x8 v; } bu;
#pragma unroll
        for (int j = 0; j < 8; ++j)
          bu.u[j] = sV[(ks * 32 + quad * 8 + j) * 64 + nt * 16 + l15];
        o[nt] = __builtin_amdgcn_mfma_f32_16x16x32_bf16(a, bu.v, o[nt], 0, 0, 0);
      }
    }
  }

  // epilogue: normalize; rows with no valid key -> 0 (guarded against 0-div)
#pragma unroll
  for (int r = 0; r < 4; ++r) {
    float inv = (m[r] > -0.9e30f && lsum[r] > 0.f) ? 1.f / lsum[r] : 0.f;
    int qrow = q0 + w * 16 + quad * 4 + r;
#pragma unroll
    for (int nt = 0; nt < 4; ++nt)
      ctx[(size_t)(b * SEQ + qrow) * E_DIM + h * HD + nt * 16 + l15] = f2b(o[nt][r] * inv);
  }
}

// ---------------- launch ----------------
// fp32 inputs / fp32 output. Internals bf16.
// d_out is 16 MB fp32 -> doubles as TWO 8 MB bf16 scratch slots (dlo, dhi).
// ws (18 MiB): bufA(8) | bufB(8) | WT x4 (2)
// Schedule (race-free liveness):
//   WT <- transpose(W*)            ws
//   qn  = LN(query)             -> dlo
//   kvn = LN(key_value)         -> bufA
//   qp  = qn @ WTq              -> dhi   (qn read from dlo)
//   kp  = kvn @ WTk             -> dlo   (qn dead)
//   vp  = kvn @ WTv             -> bufB
//   ctx = attn(qp,kp,vp)        -> bufA  (kvn dead)
//   out = ctx @ WTo + bo        -> d_out (fp32; qp/kp scratch dead)
extern "C" void kernel_launch(void* const* d_in, const int* in_sizes, int n_in,
                              void* d_out, int out_size, void* d_ws, size_t ws_size,
                              hipStream_t stream) {
  const float* query     = (const float*)d_in[0];
  const float* key_value = (const float*)d_in[1];
  const int*   kv_mask   = (const int*)d_in[2];
  const int*   sp_mask   = (const int*)d_in[3];
  const float* ln_q_g  = (const float*)d_in[4];
  const float* ln_q_b  = (const float*)d_in[5];
  const float* ln_kv_g = (const float*)d_in[6];
  const float* ln_kv_b = (const float*)d_in[7];
  const float* Wq = (const float*)d_in[8];
  const float* bq = (const float*)d_in[9];
  const float* Wk = (const float*)d_in[10];
  const float* bk = (const float*)d_in[11];
  const float* Wv = (const float*)d_in[12];
  const float* bv = (const float*)d_in[13];
  const float* Wo = (const float*)d_in[14];
  const float* bo = (const float*)d_in[15];

  const size_t NB = (size_t)NROWS * E_DIM;       // 4M bf16 elements = 8 MiB
  char* ws = (char*)d_ws;
  ushort_t* bufA = (ushort_t*)ws;                // kvn -> ctx
  ushort_t* bufB = bufA + NB;                    // vp
  ushort_t* WTq  = bufB + NB;                    // 4 x 512x512 bf16 = 2 MiB
  ushort_t* WTk = WTq + E_DIM * E_DIM;
  ushort_t* WTv = WTk + E_DIM * E_DIM;
  ushort_t* WTo = WTv + E_DIM * E_DIM;

  ushort_t* dlo = (ushort_t*)d_out;              // qn, then kp
  ushort_t* dhi = dlo + NB;                      // qp

  transpose512<<<dim3(16, 16), 256, 0, stream>>>(Wq, WTq);
  transpose512<<<dim3(16, 16), 256, 0, stream>>>(Wk, WTk);
  transpose512<<<dim3(16, 16), 256, 0, stream>>>(Wv, WTv);
  transpose512<<<dim3(16, 16), 256, 0, stream>>>(Wo, WTo);

  ln_kernel<<<2048, 256, 0, stream>>>(query, ln_q_g, ln_q_b, dlo);        // qn
  ln_kernel<<<2048, 256, 0, stream>>>(key_value, ln_kv_g, ln_kv_b, bufA); // kvn

  gemm_bias<ushort_t><<<dim3(128, 8), 256, 0, stream>>>(dlo, WTq, bq, dhi);   // qp
  gemm_bias<ushort_t><<<dim3(128, 8), 256, 0, stream>>>(bufA, WTk, bk, dlo);  // kp
  gemm_bias<ushort_t><<<dim3(128, 8), 256, 0, stream>>>(bufA, WTv, bv, bufB); // vp

  attn_kernel<<<dim3(32, HEADS, 4), 256, 0, stream>>>(dhi, dlo, bufB, kv_mask, sp_mask, bufA);

  gemm_bias<float><<<dim3(128, 8), 256, 0, stream>>>(bufA, WTo, bo, (float*)d_out);
}